// Round 8
// baseline (167.144 us; speedup 1.0000x reference)
//
#include <hip/hip_runtime.h>
#include <math.h>

#define BATCH 524288
#define NJ 12

// ws float layout:
//   [0..239]    joint consts (12 x 20)
//   [240..251]  T0 (R row-major 9, p 3)
//   [256..5631]     21 weight frags x 64 lanes x uint4 (h0..h3|l0..l3 packed f16)
//   [5632..8191]    10 bias frags x 64 lanes x f32x4
#define WOFF 256
#define BOFF 5632

typedef _Float16 half4 __attribute__((ext_vector_type(4)));
typedef _Float16 half2t __attribute__((ext_vector_type(2)));
typedef float f32x4 __attribute__((ext_vector_type(4)));

#define MFMA16(a, b, c) __builtin_amdgcn_mfma_f32_16x16x16f16((a), (b), (c), 0, 0, 0)

__device__ __forceinline__ f32x4 ld4(const float* p) { return *(const f32x4*)p; }

// runtime split via packed RTZ cvt; lo compensates hi's RTZ error (net rel err ~2^-21)
__device__ __forceinline__ void split4(f32x4 v, half4& h, half4& l) {
    half2t ha = __builtin_bit_cast(half2t, __builtin_amdgcn_cvt_pkrtz(v[0], v[1]));
    half2t hb = __builtin_bit_cast(half2t, __builtin_amdgcn_cvt_pkrtz(v[2], v[3]));
    float r0 = (v[0] - (float)ha[0]) * 2048.0f;
    float r1 = (v[1] - (float)ha[1]) * 2048.0f;
    float r2 = (v[2] - (float)hb[0]) * 2048.0f;
    float r3 = (v[3] - (float)hb[1]) * 2048.0f;
    half2t la = __builtin_bit_cast(half2t, __builtin_amdgcn_cvt_pkrtz(r0, r1));
    half2t lb = __builtin_bit_cast(half2t, __builtin_amdgcn_cvt_pkrtz(r2, r3));
    h = half4{ha[0], ha[1], hb[0], hb[1]};
    l = half4{la[0], la[1], lb[0], lb[1]};
}

__device__ __forceinline__ f32x4 relu_comb(f32x4 cH, f32x4 cL) {
    const float inv2048 = 1.0f / 2048.0f;
    f32x4 r;
#pragma unroll
    for (int i = 0; i < 4; i++) r[i] = fmaxf(fmaf(cL[i], inv2048, cH[i]), 0.0f);
    return r;
}

__device__ __forceinline__ void unpack_frag(uint4 u, half4& h, half4& l) {
    uint2 a = make_uint2(u.x, u.y), b = make_uint2(u.z, u.w);
    h = __builtin_bit_cast(half4, a);
    l = __builtin_bit_cast(half4, b);
}

__global__ void precompute_kernel(const float* __restrict__ twist,
                                  const float* __restrict__ init_p,
                                  const float* __restrict__ init_rpy,
                                  const float* __restrict__ W1, const float* __restrict__ b1,
                                  const float* __restrict__ W2, const float* __restrict__ b2,
                                  const float* __restrict__ W3, const float* __restrict__ b3,
                                  const float* __restrict__ W4, const float* __restrict__ b4,
                                  const float* __restrict__ W5, const float* __restrict__ b5,
                                  float* __restrict__ ws) {
    const int lane = threadIdx.x;       // 64 threads
    const int qd = lane >> 4, l16 = lane & 15;
    const f32x4 FZ = {0.f, 0.f, 0.f, 0.f};

    // ---- joint invariants + T0 (threads 0..12) ----
    if (lane < NJ) {
        int j = lane;
        float rho0 = twist[j*6+0], rho1 = twist[j*6+1], rho2 = twist[j*6+2];
        float w0   = twist[j*6+3], w1   = twist[j*6+4], w2   = twist[j*6+5];
        float wn = sqrtf(w0*w0 + w1*w1 + w2*w2 + 1e-12f);
        float inv = 1.0f / wn;
        float u0 = w0*inv, u1 = w1*inv, u2 = w2*inv;
        float ru0 = rho0*inv, ru1 = rho1*inv, ru2 = rho2*inv;
        float kru0 = u1*ru2 - u2*ru1;
        float kru1 = u2*ru0 - u0*ru2;
        float kru2 = u0*ru1 - u1*ru0;
        float ud = u0*ru0 + u1*ru1 + u2*ru2;
        float* o = ws + j*20;
        o[0] = wn;  o[1] = u0;  o[2] = u1;  o[3] = u2;
        o[4] = ru0; o[5] = ru1; o[6] = ru2;
        o[7] = kru0; o[8] = kru1; o[9] = kru2;
        o[10] = u0*ud - ru0; o[11] = u1*ud - ru1; o[12] = u2*ud - ru2;
        o[13] = u0*u0; o[14] = u0*u1; o[15] = u0*u2;
        o[16] = u1*u1; o[17] = u1*u2; o[18] = u2*u2;
    } else if (lane == NJ) {
        float r = init_rpy[0], p = init_rpy[1], y = init_rpy[2];
        float cr = cosf(r), sr = sinf(r);
        float cp = cosf(p), sp = sinf(p);
        float cy = cosf(y), sy = sinf(y);
        float* o = ws + NJ*20;
        o[0] = cy*cp; o[1] = cy*sp*sr - sy*cr; o[2] = cy*sp*cr + sy*sr;
        o[3] = sy*cp; o[4] = sy*sp*sr + cy*cr; o[5] = sy*sp*cr - cy*sr;
        o[6] = -sp;   o[7] = cp*sr;            o[8] = cp*cr;
        o[9] = init_p[0]; o[10] = init_p[1]; o[11] = init_p[2];
    }

    // ---- weight fragments (hi/lo split, RTN hi) ----
    uint4* wf = (uint4*)(ws + WOFF);
    f32x4* bf = (f32x4*)(ws + BOFF);

    auto pack = [&](f32x4 w) -> uint4 {
        half4 h, l;
#pragma unroll
        for (int i = 0; i < 4; i++) {
            _Float16 hi = (_Float16)w[i];
            h[i] = hi;
            l[i] = (_Float16)((w[i] - (float)hi) * 2048.0f);
        }
        uint2 uh = __builtin_bit_cast(uint2, h);
        uint2 ul = __builtin_bit_cast(uint2, l);
        return make_uint4(uh.x, uh.y, ul.x, ul.y);
    };

    // f0: a1 (K=4 padded to 16 -> only qd==0 valid)
    {
        f32x4 w = ld4(W1 + l16*4);
        wf[0*64 + lane] = pack(qd == 0 ? w : FZ);
    }
    // f1,2: a2[ot]
    for (int ot = 0; ot < 2; ot++)
        wf[(1+ot)*64 + lane] = pack(ld4(W2 + (ot*16 + l16)*16 + 4*qd));
    // f3..10: a3[ot][kc]
    for (int ot = 0; ot < 4; ot++)
        for (int kc = 0; kc < 2; kc++)
            wf[(3 + ot*2 + kc)*64 + lane] = pack(ld4(W3 + (ot*16 + l16)*32 + kc*16 + 4*qd));
    // f11..18: a4[ot][kc]
    for (int ot = 0; ot < 2; ot++)
        for (int kc = 0; kc < 4; kc++)
            wf[(11 + ot*4 + kc)*64 + lane] = pack(ld4(W4 + (ot*16 + l16)*64 + kc*16 + 4*qd));
    // f19,20: a5[kc] (rows >=12 zeroed)
    {
        int r5 = (l16 < 12) ? l16 : 11;
        for (int kc = 0; kc < 2; kc++) {
            f32x4 w = ld4(W5 + r5*32 + kc*16 + 4*qd);
            wf[(19+kc)*64 + lane] = pack(l16 < 12 ? w : FZ);
        }
    }
    // bias frags
    bf[0*64 + lane] = ld4(b1 + 4*qd);
    for (int ot = 0; ot < 2; ot++) bf[(1+ot)*64 + lane] = ld4(b2 + ot*16 + 4*qd);
    for (int ot = 0; ot < 4; ot++) bf[(3+ot)*64 + lane] = ld4(b3 + ot*16 + 4*qd);
    for (int ot = 0; ot < 2; ot++) bf[(7+ot)*64 + lane] = ld4(b4 + ot*16 + 4*qd);
    {
        f32x4 w = ld4(b5 + ((qd < 3) ? 4*qd : 8));
        bf[9*64 + lane] = (qd < 3) ? w : FZ;
    }
}

// (256,3): cap 168 unified regs, targeting 3 waves/EU. R7 at (256,2) measured
// 112 arch VGPR + ~40 acc (~150 combined) with ZERO spill — fits under 168.
// Spill tripwire: WRITE_SIZE > 32 MB means the cap bit again -> revert to (256,2).
__global__ __launch_bounds__(256, 3) void fk_kernel(
    const float* __restrict__ mc,
    const float* __restrict__ ws,
    float* __restrict__ out) {
    const int tid = threadIdx.x;
    const int wv = tid >> 6, lane = tid & 63;
    const int qd = lane >> 4, l16 = lane & 15;
    const int wave_base = (blockIdx.x * 4 + wv) * 64;

    const uint4* wf = (const uint4*)(ws + WOFF);
    const f32x4* bf = (const f32x4*)(ws + BOFF);

    // LDS: ALL 21 weight frags (21 KB) + per-wave q buffer (stride 13, ~13 KB)
    __shared__ __align__(16) uint4 wstage[21*64];
    __shared__ float qbuf[4][64*13];

    // stage weight frags once per block
    for (int i = tid; i < 21*64; i += 256) wstage[i] = wf[i];

    const half4 HZ = {(_Float16)0, (_Float16)0, (_Float16)0, (_Float16)0};
    const f32x4 FZ = {0.f, 0.f, 0.f, 0.f};

    __syncthreads();

    // Two independent 16-element chains per iteration (c = 0,1): doubles MFMA-chain
    // ILP and halves per-element ds_read/bias traffic.
#pragma unroll 1
    for (int ep = 0; ep < 2; ep++) {
        const int ebase = wave_base + ep*32 + l16;

        half4 bxh[2], bxl[2];
        {
            f32x4 xv0 = ld4(mc + (size_t)ebase * 4);
            f32x4 xv1 = ld4(mc + (size_t)(ebase + 16) * 4);
            split4(xv0, bxh[0], bxl[0]);
            split4(xv1, bxh[1], bxl[1]);
            if (qd != 0) {
                bxh[0] = HZ; bxl[0] = HZ;
                bxh[1] = HZ; bxl[1] = HZ;
            }
        }

        // Layer 1: 4 -> 16
        half4 g1h[2], g1l[2];
        {
            half4 wh, wl; unpack_frag(wstage[0*64 + lane], wh, wl);
            f32x4 bv = bf[0*64 + lane];
#pragma unroll
            for (int c = 0; c < 2; c++) {
                f32x4 aH = bv, aL = FZ;
                aH = MFMA16(wh, bxh[c], aH);
                aL = MFMA16(wh, bxl[c], aL);
                aL = MFMA16(wl, bxh[c], aL);
                split4(relu_comb(aH, aL), g1h[c], g1l[c]);
            }
        }

        // Layer 2: 16 -> 32
        half4 g2h[2][2], g2l[2][2];
#pragma unroll
        for (int ot = 0; ot < 2; ot++) {
            half4 wh, wl; unpack_frag(wstage[(1+ot)*64 + lane], wh, wl);
            f32x4 bv = bf[(1+ot)*64 + lane];
#pragma unroll
            for (int c = 0; c < 2; c++) {
                f32x4 cH = bv, cL = FZ;
                cH = MFMA16(wh, g1h[c], cH);
                cL = MFMA16(wh, g1l[c], cL);
                cL = MFMA16(wl, g1h[c], cL);
                split4(relu_comb(cH, cL), g2h[c][ot], g2l[c][ot]);
            }
        }

        // Layer 3: 32 -> 64
        half4 g3h[2][4], g3l[2][4];
#pragma unroll
        for (int ot = 0; ot < 4; ot++) {
            f32x4 bv = bf[(3+ot)*64 + lane];
            f32x4 cH[2], cL[2];
#pragma unroll
            for (int c = 0; c < 2; c++) { cH[c] = bv; cL[c] = FZ; }
#pragma unroll
            for (int kc = 0; kc < 2; kc++) {
                half4 wh, wl; unpack_frag(wstage[(3 + ot*2 + kc)*64 + lane], wh, wl);
#pragma unroll
                for (int c = 0; c < 2; c++) {
                    cH[c] = MFMA16(wh, g2h[c][kc], cH[c]);
                    cL[c] = MFMA16(wh, g2l[c][kc], cL[c]);
                    cL[c] = MFMA16(wl, g2h[c][kc], cL[c]);
                }
            }
#pragma unroll
            for (int c = 0; c < 2; c++)
                split4(relu_comb(cH[c], cL[c]), g3h[c][ot], g3l[c][ot]);
        }

        // Layer 4: 64 -> 32
        half4 g4h[2][2], g4l[2][2];
#pragma unroll
        for (int ot = 0; ot < 2; ot++) {
            f32x4 bv = bf[(7+ot)*64 + lane];
            f32x4 cH[2], cL[2];
#pragma unroll
            for (int c = 0; c < 2; c++) { cH[c] = bv; cL[c] = FZ; }
#pragma unroll
            for (int kc = 0; kc < 4; kc++) {
                half4 wh, wl; unpack_frag(wstage[(11 + ot*4 + kc)*64 + lane], wh, wl);
#pragma unroll
                for (int c = 0; c < 2; c++) {
                    cH[c] = MFMA16(wh, g3h[c][kc], cH[c]);
                    cL[c] = MFMA16(wh, g3l[c][kc], cL[c]);
                    cL[c] = MFMA16(wl, g3h[c][kc], cL[c]);
                }
            }
#pragma unroll
            for (int c = 0; c < 2; c++)
                split4(relu_comb(cH[c], cL[c]), g4h[c][ot], g4l[c][ot]);
        }

        // Layer 5: 32 -> 12. C rows are 4*qd+i: qd 0..2 hold q[0..11]; qd==3 holds
        // garbage rows 12..15 — with stride-13 qbuf its store would clobber the
        // next row's q[0..2], so mask it off.
        {
            f32x4 bv = bf[9*64 + lane];
            f32x4 cH[2], cL[2];
#pragma unroll
            for (int c = 0; c < 2; c++) { cH[c] = bv; cL[c] = FZ; }
#pragma unroll
            for (int kc = 0; kc < 2; kc++) {
                half4 wh, wl; unpack_frag(wstage[(19+kc)*64 + lane], wh, wl);
#pragma unroll
                for (int c = 0; c < 2; c++) {
                    cH[c] = MFMA16(wh, g4h[c][kc], cH[c]);
                    cL[c] = MFMA16(wh, g4l[c][kc], cL[c]);
                    cL[c] = MFMA16(wl, g4h[c][kc], cL[c]);
                }
            }
#pragma unroll
            for (int c = 0; c < 2; c++) {
                f32x4 qv = relu_comb(cH[c], cL[c]);
                if (qd < 3) {
                    float* qb = &qbuf[wv][(ep*32 + c*16 + l16)*13 + 4*qd];
                    qb[0] = qv[0]; qb[1] = qv[1]; qb[2] = qv[2]; qb[3] = qv[3];
                }
            }
        }
    }

    // q writes are wave-private; drain LDS then redistribute
    asm volatile("s_waitcnt lgkmcnt(0)" ::: "memory");

    float qq[12];
#pragma unroll
    for (int j = 0; j < 12; j++) qq[j] = qbuf[wv][lane*13 + j];

    // ---------- FK chain (fp32) ----------
    const float* jc = ws;
    float M00 = 1.f, M01 = 0.f, M02 = 0.f;
    float M10 = 0.f, M11 = 1.f, M12 = 0.f;
    float M20 = 0.f, M21 = 0.f, M22 = 1.f;
    float v0 = 0.f, v1 = 0.f, v2 = 0.f;

#pragma unroll
    for (int j = 0; j < NJ; j++) {
        const float* c = jc + j*20;
        float wn = c[0];
        float u0 = c[1], u1 = c[2], u2 = c[3];
        float ru0 = c[4], ru1 = c[5], ru2 = c[6];
        float kru0 = c[7], kru1 = c[8], kru2 = c[9];
        float k2ru0 = c[10], k2ru1 = c[11], k2ru2 = c[12];
        float uu00 = c[13], uu01 = c[14], uu02 = c[15];
        float uu11 = c[16], uu12 = c[17], uu22 = c[18];

        float th = qq[j] * wn;
        float s = __sinf(th);
        float cth = __cosf(th);
        float cc = 1.0f - cth;
        float t = th - s;

        float R00 = 1.0f + cc*(uu00 - 1.0f);
        float R01 = cc*uu01 - s*u2;
        float R02 = cc*uu02 + s*u1;
        float R10 = cc*uu01 + s*u2;
        float R11 = 1.0f + cc*(uu11 - 1.0f);
        float R12 = cc*uu12 - s*u0;
        float R20 = cc*uu02 - s*u1;
        float R21 = cc*uu12 + s*u0;
        float R22 = 1.0f + cc*(uu22 - 1.0f);

        float p0 = th*ru0 + cc*kru0 + t*k2ru0;
        float p1 = th*ru1 + cc*kru1 + t*k2ru1;
        float p2 = th*ru2 + cc*kru2 + t*k2ru2;

        float n00 = M00*R00 + M01*R10 + M02*R20;
        float n01 = M00*R01 + M01*R11 + M02*R21;
        float n02 = M00*R02 + M01*R12 + M02*R22;
        float n10 = M10*R00 + M11*R10 + M12*R20;
        float n11 = M10*R01 + M11*R11 + M12*R21;
        float n12 = M10*R02 + M11*R12 + M12*R22;
        float n20 = M20*R00 + M21*R10 + M22*R20;
        float n21 = M20*R01 + M21*R11 + M22*R21;
        float n22 = M20*R02 + M21*R12 + M22*R22;
        v0 += M00*p0 + M01*p1 + M02*p2;
        v1 += M10*p0 + M11*p1 + M12*p2;
        v2 += M20*p0 + M21*p1 + M22*p2;
        M00 = n00; M01 = n01; M02 = n02;
        M10 = n10; M11 = n11; M12 = n12;
        M20 = n20; M21 = n21; M22 = n22;
    }

    const float* t0 = jc + NJ*20;
    float A00 = t0[0], A01 = t0[1], A02 = t0[2];
    float A10 = t0[3], A11 = t0[4], A12 = t0[5];
    float A20 = t0[6], A21 = t0[7], A22 = t0[8];
    float P0  = t0[9], P1  = t0[10], P2 = t0[11];

    float F00 = M00*A00 + M01*A10 + M02*A20;
    float F01 = M00*A01 + M01*A11 + M02*A21;
    float F02 = M00*A02 + M01*A12 + M02*A22;
    float F10 = M10*A00 + M11*A10 + M12*A20;
    float F11 = M10*A01 + M11*A11 + M12*A21;
    float F12 = M10*A02 + M11*A12 + M12*A22;
    float F20 = M20*A00 + M21*A10 + M22*A20;
    float F21 = M20*A01 + M21*A11 + M22*A21;
    float F22 = M20*A02 + M21*A12 + M22*A22;
    float Fv0 = M00*P0 + M01*P1 + M02*P2 + v0;
    float Fv1 = M10*P0 + M11*P1 + M12*P2 + v1;
    float Fv2 = M20*P0 + M21*P1 + M22*P2 + v2;

    const int eo = wave_base + lane;
    float4* o4 = (float4*)(out + (size_t)eo * 16);
    o4[0] = make_float4(F00, F01, F02, Fv0);
    o4[1] = make_float4(F10, F11, F12, Fv1);
    o4[2] = make_float4(F20, F21, F22, Fv2);
    o4[3] = make_float4(0.f, 0.f, 0.f, 1.f);
}

extern "C" void kernel_launch(void* const* d_in, const int* in_sizes, int n_in,
                              void* d_out, int out_size, void* d_ws, size_t ws_size,
                              hipStream_t stream) {
    const float* mc      = (const float*)d_in[0];
    const float* W1      = (const float*)d_in[1];
    const float* b1      = (const float*)d_in[2];
    const float* W2      = (const float*)d_in[3];
    const float* b2      = (const float*)d_in[4];
    const float* W3      = (const float*)d_in[5];
    const float* b3      = (const float*)d_in[6];
    const float* W4      = (const float*)d_in[7];
    const float* b4      = (const float*)d_in[8];
    const float* W5      = (const float*)d_in[9];
    const float* b5      = (const float*)d_in[10];
    const float* twist   = (const float*)d_in[11];
    const float* init_p  = (const float*)d_in[12];
    const float* init_rpy= (const float*)d_in[13];
    float* out = (float*)d_out;
    float* ws  = (float*)d_ws;

    precompute_kernel<<<1, 64, 0, stream>>>(twist, init_p, init_rpy,
                                            W1, b1, W2, b2, W3, b3, W4, b4, W5, b5, ws);
    fk_kernel<<<BATCH / 256, 256, 0, stream>>>(mc, ws, out);
}

// Round 9
// 159.870 us; speedup vs baseline: 1.0455x; 1.0455x over previous
//
#include <hip/hip_runtime.h>
#include <math.h>

#define BATCH 524288
#define NJ 12

// ws float layout:
//   [0..239]    joint consts (12 x 20)
//   [240..251]  T0 (R row-major 9, p 3)
//   [256..5631]     21 weight frags x 64 lanes x uint4 (h0..h3|l0..l3 packed f16, lo UNSCALED)
//   [5632..8191]    10 bias frags x 64 lanes x f32x4
#define WOFF 256
#define BOFF 5632

typedef _Float16 half4 __attribute__((ext_vector_type(4)));
typedef _Float16 half2t __attribute__((ext_vector_type(2)));
typedef float f32x4 __attribute__((ext_vector_type(4)));

#define MFMA16(a, b, c) __builtin_amdgcn_mfma_f32_16x16x16f16((a), (b), (c), 0, 0, 0)

__device__ __forceinline__ f32x4 ld4(const float* p) { return *(const f32x4*)p; }

// hi = RTZ f16 of v; lo = f16(v - hi), UNSCALED (sub is exact in f32 since
// |lo| <= 2^-10 |v|; tiny residuals may be f16-denormal — MFMA either honors
// them or flushes with <=6e-5 abs error, well inside the error budget).
__device__ __forceinline__ void split4(f32x4 v, half4& h, half4& l) {
    half2t ha = __builtin_bit_cast(half2t, __builtin_amdgcn_cvt_pkrtz(v[0], v[1]));
    half2t hb = __builtin_bit_cast(half2t, __builtin_amdgcn_cvt_pkrtz(v[2], v[3]));
    float r0 = v[0] - (float)ha[0];
    float r1 = v[1] - (float)ha[1];
    float r2 = v[2] - (float)hb[0];
    float r3 = v[3] - (float)hb[1];
    half2t la = __builtin_bit_cast(half2t, __builtin_amdgcn_cvt_pkrtz(r0, r1));
    half2t lb = __builtin_bit_cast(half2t, __builtin_amdgcn_cvt_pkrtz(r2, r3));
    h = half4{ha[0], ha[1], hb[0], hb[1]};
    l = half4{la[0], la[1], lb[0], lb[1]};
}

__device__ __forceinline__ f32x4 relu4(f32x4 v) {
    f32x4 r;
#pragma unroll
    for (int i = 0; i < 4; i++) r[i] = fmaxf(v[i], 0.0f);
    return r;
}

__device__ __forceinline__ void unpack_frag(uint4 u, half4& h, half4& l) {
    uint2 a = make_uint2(u.x, u.y), b = make_uint2(u.z, u.w);
    h = __builtin_bit_cast(half4, a);
    l = __builtin_bit_cast(half4, b);
}

__global__ void precompute_kernel(const float* __restrict__ twist,
                                  const float* __restrict__ init_p,
                                  const float* __restrict__ init_rpy,
                                  const float* __restrict__ W1, const float* __restrict__ b1,
                                  const float* __restrict__ W2, const float* __restrict__ b2,
                                  const float* __restrict__ W3, const float* __restrict__ b3,
                                  const float* __restrict__ W4, const float* __restrict__ b4,
                                  const float* __restrict__ W5, const float* __restrict__ b5,
                                  float* __restrict__ ws) {
    const int lane = threadIdx.x;       // 64 threads
    const int qd = lane >> 4, l16 = lane & 15;
    const f32x4 FZ = {0.f, 0.f, 0.f, 0.f};

    // ---- joint invariants + T0 (threads 0..12) ----
    if (lane < NJ) {
        int j = lane;
        float rho0 = twist[j*6+0], rho1 = twist[j*6+1], rho2 = twist[j*6+2];
        float w0   = twist[j*6+3], w1   = twist[j*6+4], w2   = twist[j*6+5];
        float wn = sqrtf(w0*w0 + w1*w1 + w2*w2 + 1e-12f);
        float inv = 1.0f / wn;
        float u0 = w0*inv, u1 = w1*inv, u2 = w2*inv;
        float ru0 = rho0*inv, ru1 = rho1*inv, ru2 = rho2*inv;
        float kru0 = u1*ru2 - u2*ru1;
        float kru1 = u2*ru0 - u0*ru2;
        float kru2 = u0*ru1 - u1*ru0;
        float ud = u0*ru0 + u1*ru1 + u2*ru2;
        float* o = ws + j*20;
        o[0] = wn;  o[1] = u0;  o[2] = u1;  o[3] = u2;
        o[4] = ru0; o[5] = ru1; o[6] = ru2;
        o[7] = kru0; o[8] = kru1; o[9] = kru2;
        o[10] = u0*ud - ru0; o[11] = u1*ud - ru1; o[12] = u2*ud - ru2;
        o[13] = u0*u0; o[14] = u0*u1; o[15] = u0*u2;
        o[16] = u1*u1; o[17] = u1*u2; o[18] = u2*u2;
    } else if (lane == NJ) {
        float r = init_rpy[0], p = init_rpy[1], y = init_rpy[2];
        float cr = cosf(r), sr = sinf(r);
        float cp = cosf(p), sp = sinf(p);
        float cy = cosf(y), sy = sinf(y);
        float* o = ws + NJ*20;
        o[0] = cy*cp; o[1] = cy*sp*sr - sy*cr; o[2] = cy*sp*cr + sy*sr;
        o[3] = sy*cp; o[4] = sy*sp*sr + cy*cr; o[5] = sy*sp*cr - cy*sr;
        o[6] = -sp;   o[7] = cp*sr;            o[8] = cp*cr;
        o[9] = init_p[0]; o[10] = init_p[1]; o[11] = init_p[2];
    }

    // ---- weight fragments (hi/lo split, lo UNSCALED residual) ----
    uint4* wf = (uint4*)(ws + WOFF);
    f32x4* bf = (f32x4*)(ws + BOFF);

    auto pack = [&](f32x4 w) -> uint4 {
        half4 h, l;
#pragma unroll
        for (int i = 0; i < 4; i++) {
            _Float16 hi = (_Float16)w[i];
            h[i] = hi;
            l[i] = (_Float16)(w[i] - (float)hi);
        }
        uint2 uh = __builtin_bit_cast(uint2, h);
        uint2 ul = __builtin_bit_cast(uint2, l);
        return make_uint4(uh.x, uh.y, ul.x, ul.y);
    };

    // f0: a1 (K=4 padded to 16 -> only qd==0 valid)
    {
        f32x4 w = ld4(W1 + l16*4);
        wf[0*64 + lane] = pack(qd == 0 ? w : FZ);
    }
    // f1,2: a2[ot]
    for (int ot = 0; ot < 2; ot++)
        wf[(1+ot)*64 + lane] = pack(ld4(W2 + (ot*16 + l16)*16 + 4*qd));
    // f3..10: a3[ot][kc]
    for (int ot = 0; ot < 4; ot++)
        for (int kc = 0; kc < 2; kc++)
            wf[(3 + ot*2 + kc)*64 + lane] = pack(ld4(W3 + (ot*16 + l16)*32 + kc*16 + 4*qd));
    // f11..18: a4[ot][kc]
    for (int ot = 0; ot < 2; ot++)
        for (int kc = 0; kc < 4; kc++)
            wf[(11 + ot*4 + kc)*64 + lane] = pack(ld4(W4 + (ot*16 + l16)*64 + kc*16 + 4*qd));
    // f19,20: a5[kc] (rows >=12 zeroed)
    {
        int r5 = (l16 < 12) ? l16 : 11;
        for (int kc = 0; kc < 2; kc++) {
            f32x4 w = ld4(W5 + r5*32 + kc*16 + 4*qd);
            wf[(19+kc)*64 + lane] = pack(l16 < 12 ? w : FZ);
        }
    }
    // bias frags
    bf[0*64 + lane] = ld4(b1 + 4*qd);
    for (int ot = 0; ot < 2; ot++) bf[(1+ot)*64 + lane] = ld4(b2 + ot*16 + 4*qd);
    for (int ot = 0; ot < 4; ot++) bf[(3+ot)*64 + lane] = ld4(b3 + ot*16 + 4*qd);
    for (int ot = 0; ot < 2; ot++) bf[(7+ot)*64 + lane] = ld4(b4 + ot*16 + 4*qd);
    {
        f32x4 w = ld4(b5 + ((qd < 3) ? 4*qd : 8));
        bf[9*64 + lane] = (qd < 3) ? w : FZ;
    }
}

// (256,3): retry the 168-reg cap now that the single-accumulator scheme dropped
// ~16-24 unified regs (no cL accumulators, no combine temps). Spill history:
// (256,4)=128 cap -> 320MB spill; (256,3) w/ dual-acc -> 115-150MB; (256,2) clean.
// Tripwire: WRITE_SIZE > 50 MB => spill again => revert to (256,2) only.
__global__ __launch_bounds__(256, 3) void fk_kernel(
    const float* __restrict__ mc,
    const float* __restrict__ ws,
    float* __restrict__ out) {
    const int tid = threadIdx.x;
    const int wv = tid >> 6, lane = tid & 63;
    const int qd = lane >> 4, l16 = lane & 15;
    const int wave_base = (blockIdx.x * 4 + wv) * 64;

    const uint4* wf = (const uint4*)(ws + WOFF);
    const f32x4* bf = (const f32x4*)(ws + BOFF);

    // LDS: ALL 21 weight frags (21 KB) + per-wave q buffer (stride 13, ~13 KB)
    __shared__ __align__(16) uint4 wstage[21*64];
    __shared__ float qbuf[4][64*13];

    // stage weight frags once per block
    for (int i = tid; i < 21*64; i += 256) wstage[i] = wf[i];

    const half4 HZ = {(_Float16)0, (_Float16)0, (_Float16)0, (_Float16)0};

    __syncthreads();

    // Two independent 16-element chains per iteration (c = 0,1): MFMA-chain ILP,
    // halves per-element ds_read/bias traffic. Each output frag accumulates all
    // three split products (wh*gh + wh*gl + wl*gh) into ONE f32 accumulator.
#pragma unroll 1
    for (int ep = 0; ep < 2; ep++) {
        const int ebase = wave_base + ep*32 + l16;

        half4 bxh[2], bxl[2];
        {
            f32x4 xv0 = ld4(mc + (size_t)ebase * 4);
            f32x4 xv1 = ld4(mc + (size_t)(ebase + 16) * 4);
            split4(xv0, bxh[0], bxl[0]);
            split4(xv1, bxh[1], bxl[1]);
            if (qd != 0) {
                bxh[0] = HZ; bxl[0] = HZ;
                bxh[1] = HZ; bxl[1] = HZ;
            }
        }

        // Layer 1: 4 -> 16
        half4 g1h[2], g1l[2];
        {
            half4 wh, wl; unpack_frag(wstage[0*64 + lane], wh, wl);
            f32x4 bv = bf[0*64 + lane];
#pragma unroll
            for (int c = 0; c < 2; c++) {
                f32x4 acc = bv;
                acc = MFMA16(wh, bxh[c], acc);
                acc = MFMA16(wh, bxl[c], acc);
                acc = MFMA16(wl, bxh[c], acc);
                split4(relu4(acc), g1h[c], g1l[c]);
            }
        }

        // Layer 2: 16 -> 32
        half4 g2h[2][2], g2l[2][2];
#pragma unroll
        for (int ot = 0; ot < 2; ot++) {
            half4 wh, wl; unpack_frag(wstage[(1+ot)*64 + lane], wh, wl);
            f32x4 bv = bf[(1+ot)*64 + lane];
#pragma unroll
            for (int c = 0; c < 2; c++) {
                f32x4 acc = bv;
                acc = MFMA16(wh, g1h[c], acc);
                acc = MFMA16(wh, g1l[c], acc);
                acc = MFMA16(wl, g1h[c], acc);
                split4(relu4(acc), g2h[c][ot], g2l[c][ot]);
            }
        }

        // Layer 3: 32 -> 64
        half4 g3h[2][4], g3l[2][4];
#pragma unroll
        for (int ot = 0; ot < 4; ot++) {
            f32x4 bv = bf[(3+ot)*64 + lane];
            f32x4 acc[2];
#pragma unroll
            for (int c = 0; c < 2; c++) acc[c] = bv;
#pragma unroll
            for (int kc = 0; kc < 2; kc++) {
                half4 wh, wl; unpack_frag(wstage[(3 + ot*2 + kc)*64 + lane], wh, wl);
#pragma unroll
                for (int c = 0; c < 2; c++) {
                    acc[c] = MFMA16(wh, g2h[c][kc], acc[c]);
                    acc[c] = MFMA16(wh, g2l[c][kc], acc[c]);
                    acc[c] = MFMA16(wl, g2h[c][kc], acc[c]);
                }
            }
#pragma unroll
            for (int c = 0; c < 2; c++)
                split4(relu4(acc[c]), g3h[c][ot], g3l[c][ot]);
        }

        // Layer 4: 64 -> 32
        half4 g4h[2][2], g4l[2][2];
#pragma unroll
        for (int ot = 0; ot < 2; ot++) {
            f32x4 bv = bf[(7+ot)*64 + lane];
            f32x4 acc[2];
#pragma unroll
            for (int c = 0; c < 2; c++) acc[c] = bv;
#pragma unroll
            for (int kc = 0; kc < 4; kc++) {
                half4 wh, wl; unpack_frag(wstage[(11 + ot*4 + kc)*64 + lane], wh, wl);
#pragma unroll
                for (int c = 0; c < 2; c++) {
                    acc[c] = MFMA16(wh, g3h[c][kc], acc[c]);
                    acc[c] = MFMA16(wh, g3l[c][kc], acc[c]);
                    acc[c] = MFMA16(wl, g3h[c][kc], acc[c]);
                }
            }
#pragma unroll
            for (int c = 0; c < 2; c++)
                split4(relu4(acc[c]), g4h[c][ot], g4l[c][ot]);
        }

        // Layer 5: 32 -> 12. C rows are 4*qd+i: qd 0..2 hold q[0..11]; qd==3 holds
        // garbage rows 12..15 — with stride-13 qbuf its store would clobber the
        // next row's q[0..2], so mask it off.
        {
            f32x4 bv = bf[9*64 + lane];
            f32x4 acc[2];
#pragma unroll
            for (int c = 0; c < 2; c++) acc[c] = bv;
#pragma unroll
            for (int kc = 0; kc < 2; kc++) {
                half4 wh, wl; unpack_frag(wstage[(19+kc)*64 + lane], wh, wl);
#pragma unroll
                for (int c = 0; c < 2; c++) {
                    acc[c] = MFMA16(wh, g4h[c][kc], acc[c]);
                    acc[c] = MFMA16(wh, g4l[c][kc], acc[c]);
                    acc[c] = MFMA16(wl, g4h[c][kc], acc[c]);
                }
            }
#pragma unroll
            for (int c = 0; c < 2; c++) {
                f32x4 qv = relu4(acc[c]);
                if (qd < 3) {
                    float* qb = &qbuf[wv][(ep*32 + c*16 + l16)*13 + 4*qd];
                    qb[0] = qv[0]; qb[1] = qv[1]; qb[2] = qv[2]; qb[3] = qv[3];
                }
            }
        }
    }

    // q writes are wave-private; drain LDS then redistribute
    asm volatile("s_waitcnt lgkmcnt(0)" ::: "memory");

    float qq[12];
#pragma unroll
    for (int j = 0; j < 12; j++) qq[j] = qbuf[wv][lane*13 + j];

    // ---------- FK chain (fp32) ----------
    const float* jc = ws;
    float M00 = 1.f, M01 = 0.f, M02 = 0.f;
    float M10 = 0.f, M11 = 1.f, M12 = 0.f;
    float M20 = 0.f, M21 = 0.f, M22 = 1.f;
    float v0 = 0.f, v1 = 0.f, v2 = 0.f;

#pragma unroll
    for (int j = 0; j < NJ; j++) {
        const float* c = jc + j*20;
        float wn = c[0];
        float u0 = c[1], u1 = c[2], u2 = c[3];
        float ru0 = c[4], ru1 = c[5], ru2 = c[6];
        float kru0 = c[7], kru1 = c[8], kru2 = c[9];
        float k2ru0 = c[10], k2ru1 = c[11], k2ru2 = c[12];
        float uu00 = c[13], uu01 = c[14], uu02 = c[15];
        float uu11 = c[16], uu12 = c[17], uu22 = c[18];

        float th = qq[j] * wn;
        float s = __sinf(th);
        float cth = __cosf(th);
        float cc = 1.0f - cth;
        float t = th - s;

        float R00 = 1.0f + cc*(uu00 - 1.0f);
        float R01 = cc*uu01 - s*u2;
        float R02 = cc*uu02 + s*u1;
        float R10 = cc*uu01 + s*u2;
        float R11 = 1.0f + cc*(uu11 - 1.0f);
        float R12 = cc*uu12 - s*u0;
        float R20 = cc*uu02 - s*u1;
        float R21 = cc*uu12 + s*u0;
        float R22 = 1.0f + cc*(uu22 - 1.0f);

        float p0 = th*ru0 + cc*kru0 + t*k2ru0;
        float p1 = th*ru1 + cc*kru1 + t*k2ru1;
        float p2 = th*ru2 + cc*kru2 + t*k2ru2;

        float n00 = M00*R00 + M01*R10 + M02*R20;
        float n01 = M00*R01 + M01*R11 + M02*R21;
        float n02 = M00*R02 + M01*R12 + M02*R22;
        float n10 = M10*R00 + M11*R10 + M12*R20;
        float n11 = M10*R01 + M11*R11 + M12*R21;
        float n12 = M10*R02 + M11*R12 + M12*R22;
        float n20 = M20*R00 + M21*R10 + M22*R20;
        float n21 = M20*R01 + M21*R11 + M22*R21;
        float n22 = M20*R02 + M21*R12 + M22*R22;
        v0 += M00*p0 + M01*p1 + M02*p2;
        v1 += M10*p0 + M11*p1 + M12*p2;
        v2 += M20*p0 + M21*p1 + M22*p2;
        M00 = n00; M01 = n01; M02 = n02;
        M10 = n10; M11 = n11; M12 = n12;
        M20 = n20; M21 = n21; M22 = n22;
    }

    const float* t0 = jc + NJ*20;
    float A00 = t0[0], A01 = t0[1], A02 = t0[2];
    float A10 = t0[3], A11 = t0[4], A12 = t0[5];
    float A20 = t0[6], A21 = t0[7], A22 = t0[8];
    float P0  = t0[9], P1  = t0[10], P2 = t0[11];

    float F00 = M00*A00 + M01*A10 + M02*A20;
    float F01 = M00*A01 + M01*A11 + M02*A21;
    float F02 = M00*A02 + M01*A12 + M02*A22;
    float F10 = M10*A00 + M11*A10 + M12*A20;
    float F11 = M10*A01 + M11*A11 + M12*A21;
    float F12 = M10*A02 + M11*A12 + M12*A22;
    float F20 = M20*A00 + M21*A10 + M22*A20;
    float F21 = M20*A01 + M21*A11 + M22*A21;
    float F22 = M20*A02 + M21*A12 + M22*A22;
    float Fv0 = M00*P0 + M01*P1 + M02*P2 + v0;
    float Fv1 = M10*P0 + M11*P1 + M12*P2 + v1;
    float Fv2 = M20*P0 + M21*P1 + M22*P2 + v2;

    const int eo = wave_base + lane;
    float4* o4 = (float4*)(out + (size_t)eo * 16);
    o4[0] = make_float4(F00, F01, F02, Fv0);
    o4[1] = make_float4(F10, F11, F12, Fv1);
    o4[2] = make_float4(F20, F21, F22, Fv2);
    o4[3] = make_float4(0.f, 0.f, 0.f, 1.f);
}

extern "C" void kernel_launch(void* const* d_in, const int* in_sizes, int n_in,
                              void* d_out, int out_size, void* d_ws, size_t ws_size,
                              hipStream_t stream) {
    const float* mc      = (const float*)d_in[0];
    const float* W1      = (const float*)d_in[1];
    const float* b1      = (const float*)d_in[2];
    const float* W2      = (const float*)d_in[3];
    const float* b2      = (const float*)d_in[4];
    const float* W3      = (const float*)d_in[5];
    const float* b3      = (const float*)d_in[6];
    const float* W4      = (const float*)d_in[7];
    const float* b4      = (const float*)d_in[8];
    const float* W5      = (const float*)d_in[9];
    const float* b5      = (const float*)d_in[10];
    const float* twist   = (const float*)d_in[11];
    const float* init_p  = (const float*)d_in[12];
    const float* init_rpy= (const float*)d_in[13];
    float* out = (float*)d_out;
    float* ws  = (float*)d_ws;

    precompute_kernel<<<1, 64, 0, stream>>>(twist, init_p, init_rpy,
                                            W1, b1, W2, b2, W3, b3, W4, b4, W5, b5, ws);
    fk_kernel<<<BATCH / 256, 256, 0, stream>>>(mc, ws, out);
}

// Round 10
// 137.340 us; speedup vs baseline: 1.2170x; 1.1640x over previous
//
#include <hip/hip_runtime.h>
#include <math.h>

#define BATCH 524288
#define NJ 12

// ws float layout:
//   [0..239]    joint consts (12 x 20)
//   [240..251]  T0 (R row-major 9, p 3)
//   [256..5631]     21 weight frags x 64 lanes x uint4 (h0..h3|l0..l3 packed f16, lo UNSCALED)
//   [5632..8191]    10 bias frags x 64 lanes x f32x4
#define WOFF 256
#define BOFF 5632

typedef _Float16 half4 __attribute__((ext_vector_type(4)));
typedef _Float16 half2t __attribute__((ext_vector_type(2)));
typedef float f32x4 __attribute__((ext_vector_type(4)));

#define MFMA16(a, b, c) __builtin_amdgcn_mfma_f32_16x16x16f16((a), (b), (c), 0, 0, 0)

__device__ __forceinline__ f32x4 ld4(const float* p) { return *(const f32x4*)p; }

// hi = RTZ f16 of v; lo = f16(v - hi), UNSCALED (residual below f16-normal is
// flushed with <=6e-5 abs error — inside budget; measured absmax 0.0078).
__device__ __forceinline__ void split4(f32x4 v, half4& h, half4& l) {
    half2t ha = __builtin_bit_cast(half2t, __builtin_amdgcn_cvt_pkrtz(v[0], v[1]));
    half2t hb = __builtin_bit_cast(half2t, __builtin_amdgcn_cvt_pkrtz(v[2], v[3]));
    float r0 = v[0] - (float)ha[0];
    float r1 = v[1] - (float)ha[1];
    float r2 = v[2] - (float)hb[0];
    float r3 = v[3] - (float)hb[1];
    half2t la = __builtin_bit_cast(half2t, __builtin_amdgcn_cvt_pkrtz(r0, r1));
    half2t lb = __builtin_bit_cast(half2t, __builtin_amdgcn_cvt_pkrtz(r2, r3));
    h = half4{ha[0], ha[1], hb[0], hb[1]};
    l = half4{la[0], la[1], lb[0], lb[1]};
}

__device__ __forceinline__ f32x4 relu4(f32x4 v) {
    f32x4 r;
#pragma unroll
    for (int i = 0; i < 4; i++) r[i] = fmaxf(v[i], 0.0f);
    return r;
}

__device__ __forceinline__ void unpack_frag(uint4 u, half4& h, half4& l) {
    uint2 a = make_uint2(u.x, u.y), b = make_uint2(u.z, u.w);
    h = __builtin_bit_cast(half4, a);
    l = __builtin_bit_cast(half4, b);
}

__global__ void precompute_kernel(const float* __restrict__ twist,
                                  const float* __restrict__ init_p,
                                  const float* __restrict__ init_rpy,
                                  const float* __restrict__ W1, const float* __restrict__ b1,
                                  const float* __restrict__ W2, const float* __restrict__ b2,
                                  const float* __restrict__ W3, const float* __restrict__ b3,
                                  const float* __restrict__ W4, const float* __restrict__ b4,
                                  const float* __restrict__ W5, const float* __restrict__ b5,
                                  float* __restrict__ ws) {
    const int lane = threadIdx.x;       // 64 threads
    const int qd = lane >> 4, l16 = lane & 15;
    const f32x4 FZ = {0.f, 0.f, 0.f, 0.f};

    // ---- joint invariants + T0 (threads 0..12) ----
    if (lane < NJ) {
        int j = lane;
        float rho0 = twist[j*6+0], rho1 = twist[j*6+1], rho2 = twist[j*6+2];
        float w0   = twist[j*6+3], w1   = twist[j*6+4], w2   = twist[j*6+5];
        float wn = sqrtf(w0*w0 + w1*w1 + w2*w2 + 1e-12f);
        float inv = 1.0f / wn;
        float u0 = w0*inv, u1 = w1*inv, u2 = w2*inv;
        float ru0 = rho0*inv, ru1 = rho1*inv, ru2 = rho2*inv;
        float kru0 = u1*ru2 - u2*ru1;
        float kru1 = u2*ru0 - u0*ru2;
        float kru2 = u0*ru1 - u1*ru0;
        float ud = u0*ru0 + u1*ru1 + u2*ru2;
        float* o = ws + j*20;
        o[0] = wn;  o[1] = u0;  o[2] = u1;  o[3] = u2;
        o[4] = ru0; o[5] = ru1; o[6] = ru2;
        o[7] = kru0; o[8] = kru1; o[9] = kru2;
        o[10] = u0*ud - ru0; o[11] = u1*ud - ru1; o[12] = u2*ud - ru2;
        o[13] = u0*u0; o[14] = u0*u1; o[15] = u0*u2;
        o[16] = u1*u1; o[17] = u1*u2; o[18] = u2*u2;
    } else if (lane == NJ) {
        float r = init_rpy[0], p = init_rpy[1], y = init_rpy[2];
        float cr = cosf(r), sr = sinf(r);
        float cp = cosf(p), sp = sinf(p);
        float cy = cosf(y), sy = sinf(y);
        float* o = ws + NJ*20;
        o[0] = cy*cp; o[1] = cy*sp*sr - sy*cr; o[2] = cy*sp*cr + sy*sr;
        o[3] = sy*cp; o[4] = sy*sp*sr + cy*cr; o[5] = sy*sp*cr - cy*sr;
        o[6] = -sp;   o[7] = cp*sr;            o[8] = cp*cr;
        o[9] = init_p[0]; o[10] = init_p[1]; o[11] = init_p[2];
    }

    // ---- weight fragments (hi/lo split, lo UNSCALED residual) ----
    uint4* wf = (uint4*)(ws + WOFF);
    f32x4* bf = (f32x4*)(ws + BOFF);

    auto pack = [&](f32x4 w) -> uint4 {
        half4 h, l;
#pragma unroll
        for (int i = 0; i < 4; i++) {
            _Float16 hi = (_Float16)w[i];
            h[i] = hi;
            l[i] = (_Float16)(w[i] - (float)hi);
        }
        uint2 uh = __builtin_bit_cast(uint2, h);
        uint2 ul = __builtin_bit_cast(uint2, l);
        return make_uint4(uh.x, uh.y, ul.x, ul.y);
    };

    // f0: a1 (K=4 padded to 16 -> only qd==0 valid)
    {
        f32x4 w = ld4(W1 + l16*4);
        wf[0*64 + lane] = pack(qd == 0 ? w : FZ);
    }
    // f1,2: a2[ot]
    for (int ot = 0; ot < 2; ot++)
        wf[(1+ot)*64 + lane] = pack(ld4(W2 + (ot*16 + l16)*16 + 4*qd));
    // f3..10: a3[ot][kc]
    for (int ot = 0; ot < 4; ot++)
        for (int kc = 0; kc < 2; kc++)
            wf[(3 + ot*2 + kc)*64 + lane] = pack(ld4(W3 + (ot*16 + l16)*32 + kc*16 + 4*qd));
    // f11..18: a4[ot][kc]
    for (int ot = 0; ot < 2; ot++)
        for (int kc = 0; kc < 4; kc++)
            wf[(11 + ot*4 + kc)*64 + lane] = pack(ld4(W4 + (ot*16 + l16)*64 + kc*16 + 4*qd));
    // f19,20: a5[kc] (rows >=12 zeroed)
    {
        int r5 = (l16 < 12) ? l16 : 11;
        for (int kc = 0; kc < 2; kc++) {
            f32x4 w = ld4(W5 + r5*32 + kc*16 + 4*qd);
            wf[(19+kc)*64 + lane] = pack(l16 < 12 ? w : FZ);
        }
    }
    // bias frags
    bf[0*64 + lane] = ld4(b1 + 4*qd);
    for (int ot = 0; ot < 2; ot++) bf[(1+ot)*64 + lane] = ld4(b2 + ot*16 + 4*qd);
    for (int ot = 0; ot < 4; ot++) bf[(3+ot)*64 + lane] = ld4(b3 + ot*16 + 4*qd);
    for (int ot = 0; ot < 2; ot++) bf[(7+ot)*64 + lane] = ld4(b4 + ot*16 + 4*qd);
    {
        f32x4 w = ld4(b5 + ((qd < 3) ? 4*qd : 8));
        bf[9*64 + lane] = (qd < 3) ? w : FZ;
    }
}

// (256,2): the ONLY spill-free cap for this structure (verified R7: WRITE=32MB).
// (256,4)/(256,3) spill 320/115-149 MB of scratch — unified VGPR+AGPR partitions
// exceed the cap. Latency hiding comes from 2-chain ILP, not occupancy.
__global__ __launch_bounds__(256, 2) void fk_kernel(
    const float* __restrict__ mc,
    const float* __restrict__ ws,
    float* __restrict__ out) {
    const int tid = threadIdx.x;
    const int wv = tid >> 6, lane = tid & 63;
    const int qd = lane >> 4, l16 = lane & 15;
    const int wave_base = (blockIdx.x * 4 + wv) * 64;

    const uint4* wf = (const uint4*)(ws + WOFF);
    const f32x4* bf = (const f32x4*)(ws + BOFF);

    // LDS: ALL 21 weight frags (21 KB) + per-wave q buffer (stride 13, ~13 KB)
    __shared__ __align__(16) uint4 wstage[21*64];
    __shared__ float qbuf[4][64*13];

    // stage weight frags once per block
    for (int i = tid; i < 21*64; i += 256) wstage[i] = wf[i];

    const half4 HZ = {(_Float16)0, (_Float16)0, (_Float16)0, (_Float16)0};

    __syncthreads();

    // Two independent 16-element chains per iteration (c = 0,1): MFMA-chain ILP,
    // halves per-element ds_read/bias traffic. Each output frag accumulates all
    // three split products (wh*gh + wh*gl + wl*gh) into ONE f32 accumulator.
#pragma unroll 1
    for (int ep = 0; ep < 2; ep++) {
        const int ebase = wave_base + ep*32 + l16;

        half4 bxh[2], bxl[2];
        {
            f32x4 xv0 = ld4(mc + (size_t)ebase * 4);
            f32x4 xv1 = ld4(mc + (size_t)(ebase + 16) * 4);
            split4(xv0, bxh[0], bxl[0]);
            split4(xv1, bxh[1], bxl[1]);
            if (qd != 0) {
                bxh[0] = HZ; bxl[0] = HZ;
                bxh[1] = HZ; bxl[1] = HZ;
            }
        }

        // Layer 1: 4 -> 16
        half4 g1h[2], g1l[2];
        {
            half4 wh, wl; unpack_frag(wstage[0*64 + lane], wh, wl);
            f32x4 bv = bf[0*64 + lane];
#pragma unroll
            for (int c = 0; c < 2; c++) {
                f32x4 acc = bv;
                acc = MFMA16(wh, bxh[c], acc);
                acc = MFMA16(wh, bxl[c], acc);
                acc = MFMA16(wl, bxh[c], acc);
                split4(relu4(acc), g1h[c], g1l[c]);
            }
        }

        // Layer 2: 16 -> 32
        half4 g2h[2][2], g2l[2][2];
#pragma unroll
        for (int ot = 0; ot < 2; ot++) {
            half4 wh, wl; unpack_frag(wstage[(1+ot)*64 + lane], wh, wl);
            f32x4 bv = bf[(1+ot)*64 + lane];
#pragma unroll
            for (int c = 0; c < 2; c++) {
                f32x4 acc = bv;
                acc = MFMA16(wh, g1h[c], acc);
                acc = MFMA16(wh, g1l[c], acc);
                acc = MFMA16(wl, g1h[c], acc);
                split4(relu4(acc), g2h[c][ot], g2l[c][ot]);
            }
        }

        // Layer 3: 32 -> 64
        half4 g3h[2][4], g3l[2][4];
#pragma unroll
        for (int ot = 0; ot < 4; ot++) {
            f32x4 bv = bf[(3+ot)*64 + lane];
            f32x4 acc[2];
#pragma unroll
            for (int c = 0; c < 2; c++) acc[c] = bv;
#pragma unroll
            for (int kc = 0; kc < 2; kc++) {
                half4 wh, wl; unpack_frag(wstage[(3 + ot*2 + kc)*64 + lane], wh, wl);
#pragma unroll
                for (int c = 0; c < 2; c++) {
                    acc[c] = MFMA16(wh, g2h[c][kc], acc[c]);
                    acc[c] = MFMA16(wh, g2l[c][kc], acc[c]);
                    acc[c] = MFMA16(wl, g2h[c][kc], acc[c]);
                }
            }
#pragma unroll
            for (int c = 0; c < 2; c++)
                split4(relu4(acc[c]), g3h[c][ot], g3l[c][ot]);
        }

        // Layer 4: 64 -> 32
        half4 g4h[2][2], g4l[2][2];
#pragma unroll
        for (int ot = 0; ot < 2; ot++) {
            f32x4 bv = bf[(7+ot)*64 + lane];
            f32x4 acc[2];
#pragma unroll
            for (int c = 0; c < 2; c++) acc[c] = bv;
#pragma unroll
            for (int kc = 0; kc < 4; kc++) {
                half4 wh, wl; unpack_frag(wstage[(11 + ot*4 + kc)*64 + lane], wh, wl);
#pragma unroll
                for (int c = 0; c < 2; c++) {
                    acc[c] = MFMA16(wh, g3h[c][kc], acc[c]);
                    acc[c] = MFMA16(wh, g3l[c][kc], acc[c]);
                    acc[c] = MFMA16(wl, g3h[c][kc], acc[c]);
                }
            }
#pragma unroll
            for (int c = 0; c < 2; c++)
                split4(relu4(acc[c]), g4h[c][ot], g4l[c][ot]);
        }

        // Layer 5: 32 -> 12. C rows are 4*qd+i: qd 0..2 hold q[0..11]; qd==3 holds
        // garbage rows 12..15 — with stride-13 qbuf its store would clobber the
        // next row's q[0..2], so mask it off.
        {
            f32x4 bv = bf[9*64 + lane];
            f32x4 acc[2];
#pragma unroll
            for (int c = 0; c < 2; c++) acc[c] = bv;
#pragma unroll
            for (int kc = 0; kc < 2; kc++) {
                half4 wh, wl; unpack_frag(wstage[(19+kc)*64 + lane], wh, wl);
#pragma unroll
                for (int c = 0; c < 2; c++) {
                    acc[c] = MFMA16(wh, g4h[c][kc], acc[c]);
                    acc[c] = MFMA16(wh, g4l[c][kc], acc[c]);
                    acc[c] = MFMA16(wl, g4h[c][kc], acc[c]);
                }
            }
#pragma unroll
            for (int c = 0; c < 2; c++) {
                f32x4 qv = relu4(acc[c]);
                if (qd < 3) {
                    float* qb = &qbuf[wv][(ep*32 + c*16 + l16)*13 + 4*qd];
                    qb[0] = qv[0]; qb[1] = qv[1]; qb[2] = qv[2]; qb[3] = qv[3];
                }
            }
        }
    }

    // q writes are wave-private; drain LDS then redistribute
    asm volatile("s_waitcnt lgkmcnt(0)" ::: "memory");

    float qq[12];
#pragma unroll
    for (int j = 0; j < 12; j++) qq[j] = qbuf[wv][lane*13 + j];

    // ---------- FK chain (fp32) ----------
    const float* jc = ws;
    float M00 = 1.f, M01 = 0.f, M02 = 0.f;
    float M10 = 0.f, M11 = 1.f, M12 = 0.f;
    float M20 = 0.f, M21 = 0.f, M22 = 1.f;
    float v0 = 0.f, v1 = 0.f, v2 = 0.f;

#pragma unroll
    for (int j = 0; j < NJ; j++) {
        const float* c = jc + j*20;
        float wn = c[0];
        float u0 = c[1], u1 = c[2], u2 = c[3];
        float ru0 = c[4], ru1 = c[5], ru2 = c[6];
        float kru0 = c[7], kru1 = c[8], kru2 = c[9];
        float k2ru0 = c[10], k2ru1 = c[11], k2ru2 = c[12];
        float uu00 = c[13], uu01 = c[14], uu02 = c[15];
        float uu11 = c[16], uu12 = c[17], uu22 = c[18];

        float th = qq[j] * wn;
        float s = __sinf(th);
        float cth = __cosf(th);
        float cc = 1.0f - cth;
        float t = th - s;

        float R00 = 1.0f + cc*(uu00 - 1.0f);
        float R01 = cc*uu01 - s*u2;
        float R02 = cc*uu02 + s*u1;
        float R10 = cc*uu01 + s*u2;
        float R11 = 1.0f + cc*(uu11 - 1.0f);
        float R12 = cc*uu12 - s*u0;
        float R20 = cc*uu02 - s*u1;
        float R21 = cc*uu12 + s*u0;
        float R22 = 1.0f + cc*(uu22 - 1.0f);

        float p0 = th*ru0 + cc*kru0 + t*k2ru0;
        float p1 = th*ru1 + cc*kru1 + t*k2ru1;
        float p2 = th*ru2 + cc*kru2 + t*k2ru2;

        float n00 = M00*R00 + M01*R10 + M02*R20;
        float n01 = M00*R01 + M01*R11 + M02*R21;
        float n02 = M00*R02 + M01*R12 + M02*R22;
        float n10 = M10*R00 + M11*R10 + M12*R20;
        float n11 = M10*R01 + M11*R11 + M12*R21;
        float n12 = M10*R02 + M11*R12 + M12*R22;
        float n20 = M20*R00 + M21*R10 + M22*R20;
        float n21 = M20*R01 + M21*R11 + M22*R21;
        float n22 = M20*R02 + M21*R12 + M22*R22;
        v0 += M00*p0 + M01*p1 + M02*p2;
        v1 += M10*p0 + M11*p1 + M12*p2;
        v2 += M20*p0 + M21*p1 + M22*p2;
        M00 = n00; M01 = n01; M02 = n02;
        M10 = n10; M11 = n11; M12 = n12;
        M20 = n20; M21 = n21; M22 = n22;
    }

    const float* t0 = jc + NJ*20;
    float A00 = t0[0], A01 = t0[1], A02 = t0[2];
    float A10 = t0[3], A11 = t0[4], A12 = t0[5];
    float A20 = t0[6], A21 = t0[7], A22 = t0[8];
    float P0  = t0[9], P1  = t0[10], P2 = t0[11];

    float F00 = M00*A00 + M01*A10 + M02*A20;
    float F01 = M00*A01 + M01*A11 + M02*A21;
    float F02 = M00*A02 + M01*A12 + M02*A22;
    float F10 = M10*A00 + M11*A10 + M12*A20;
    float F11 = M10*A01 + M11*A11 + M12*A21;
    float F12 = M10*A02 + M11*A12 + M12*A22;
    float F20 = M20*A00 + M21*A10 + M22*A20;
    float F21 = M20*A01 + M21*A11 + M22*A21;
    float F22 = M20*A02 + M21*A12 + M22*A22;
    float Fv0 = M00*P0 + M01*P1 + M02*P2 + v0;
    float Fv1 = M10*P0 + M11*P1 + M12*P2 + v1;
    float Fv2 = M20*P0 + M21*P1 + M22*P2 + v2;

    const int eo = wave_base + lane;
    float4* o4 = (float4*)(out + (size_t)eo * 16);
    o4[0] = make_float4(F00, F01, F02, Fv0);
    o4[1] = make_float4(F10, F11, F12, Fv1);
    o4[2] = make_float4(F20, F21, F22, Fv2);
    o4[3] = make_float4(0.f, 0.f, 0.f, 1.f);
}

extern "C" void kernel_launch(void* const* d_in, const int* in_sizes, int n_in,
                              void* d_out, int out_size, void* d_ws, size_t ws_size,
                              hipStream_t stream) {
    const float* mc      = (const float*)d_in[0];
    const float* W1      = (const float*)d_in[1];
    const float* b1      = (const float*)d_in[2];
    const float* W2      = (const float*)d_in[3];
    const float* b2      = (const float*)d_in[4];
    const float* W3      = (const float*)d_in[5];
    const float* b3      = (const float*)d_in[6];
    const float* W4      = (const float*)d_in[7];
    const float* b4      = (const float*)d_in[8];
    const float* W5      = (const float*)d_in[9];
    const float* b5      = (const float*)d_in[10];
    const float* twist   = (const float*)d_in[11];
    const float* init_p  = (const float*)d_in[12];
    const float* init_rpy= (const float*)d_in[13];
    float* out = (float*)d_out;
    float* ws  = (float*)d_ws;

    precompute_kernel<<<1, 64, 0, stream>>>(twist, init_p, init_rpy,
                                            W1, b1, W2, b2, W3, b3, W4, b4, W5, b5, ws);
    fk_kernel<<<BATCH / 256, 256, 0, stream>>>(mc, ws, out);
}